// Round 1
// baseline (429.137 us; speedup 1.0000x reference)
//
#include <hip/hip_runtime.h>

// Sparsemax along dim=-1 for x[4,4096,4096] fp32.
// tau solves sum(max(x - tau, 0)) = 1. Newton iteration on the convex
// piecewise-linear f(tau) = sum(max(x-tau,0)) - 1:
//   tau <- (sum_{x>tau} x - 1) / count_{x>tau}
// starting at tau0 = max(x) - 1 (f(tau0) >= 0). Converges finitely
// (support set strictly shrinks or iteration is exact).
// One block per row; row lives in registers (16 floats/thread).

#define ROW_D 4096
#define BLOCK 256   // 4 waves; 16 floats per thread = 4x float4

__global__ __launch_bounds__(BLOCK)
void sparsemax_rows_kernel(const float* __restrict__ x,
                           float* __restrict__ out) {
    const int row = blockIdx.x;
    const float* __restrict__ xr = x + (size_t)row * ROW_D;
    float* __restrict__ outr = out + (size_t)row * ROW_D;

    const int t = threadIdx.x;
    const int lane = t & 63;
    const int wave = t >> 6;

    // ---- load 16 elements per thread, coalesced float4 ----
    float4 v[4];
#pragma unroll
    for (int j = 0; j < 4; ++j) {
        v[j] = reinterpret_cast<const float4*>(xr)[t + j * BLOCK];
    }

    __shared__ float s_max[4];
    __shared__ float s_sum[4];
    __shared__ float s_cnt[4];
    __shared__ float s_tau;

    // ---- row max ----
    float m = fmaxf(fmaxf(v[0].x, v[0].y), fmaxf(v[0].z, v[0].w));
#pragma unroll
    for (int j = 1; j < 4; ++j) {
        m = fmaxf(m, fmaxf(fmaxf(v[j].x, v[j].y), fmaxf(v[j].z, v[j].w)));
    }
#pragma unroll
    for (int off = 32; off > 0; off >>= 1)
        m = fmaxf(m, __shfl_down(m, off, 64));
    if (lane == 0) s_max[wave] = m;
    __syncthreads();
    if (t == 0) {
        float mm = fmaxf(fmaxf(s_max[0], s_max[1]), fmaxf(s_max[2], s_max[3]));
        s_tau = mm - 1.0f;
    }
    __syncthreads();
    float tau = s_tau;

    // ---- Newton iterations (block-uniform tau; uniform break) ----
    for (int it = 0; it < 64; ++it) {
        float s = 0.0f, k = 0.0f;
#pragma unroll
        for (int j = 0; j < 4; ++j) {
            float a0 = v[j].x, a1 = v[j].y, a2 = v[j].z, a3 = v[j].w;
            if (a0 > tau) { s += a0; k += 1.0f; }
            if (a1 > tau) { s += a1; k += 1.0f; }
            if (a2 > tau) { s += a2; k += 1.0f; }
            if (a3 > tau) { s += a3; k += 1.0f; }
        }
#pragma unroll
        for (int off = 32; off > 0; off >>= 1) {
            s += __shfl_down(s, off, 64);
            k += __shfl_down(k, off, 64);
        }
        if (lane == 0) { s_sum[wave] = s; s_cnt[wave] = k; }
        __syncthreads();
        if (t == 0) {
            float ss = (s_sum[0] + s_sum[1]) + (s_sum[2] + s_sum[3]);
            float kk = (s_cnt[0] + s_cnt[1]) + (s_cnt[2] + s_cnt[3]);
            s_tau = (ss - 1.0f) / kk;   // kk >= 1 always (tau < row max)
        }
        __syncthreads();
        float ntau = s_tau;
        if (ntau == tau) break;  // bit-exact uniform convergence
        tau = ntau;
        // Next write to s_tau happens after the reduction barrier above,
        // so no extra sync needed here.
    }

    // ---- output: max(x - tau, 0), coalesced ----
#pragma unroll
    for (int j = 0; j < 4; ++j) {
        float4 o;
        o.x = fmaxf(v[j].x - tau, 0.0f);
        o.y = fmaxf(v[j].y - tau, 0.0f);
        o.z = fmaxf(v[j].z - tau, 0.0f);
        o.w = fmaxf(v[j].w - tau, 0.0f);
        reinterpret_cast<float4*>(outr)[t + j * BLOCK] = o;
    }
}

extern "C" void kernel_launch(void* const* d_in, const int* in_sizes, int n_in,
                              void* d_out, int out_size, void* d_ws, size_t ws_size,
                              hipStream_t stream) {
    const float* x = (const float*)d_in[0];
    float* out = (float*)d_out;
    const int nrows = in_sizes[0] / ROW_D;   // 4*4096 = 16384
    sparsemax_rows_kernel<<<nrows, BLOCK, 0, stream>>>(x, out);
}